// Round 4
// baseline (329.067 us; speedup 1.0000x reference)
//
#include <hip/hip_runtime.h>

#define NB 8
#define NP 65536
#define NC 32768
#define NF 32
#define NE 524288

typedef __attribute__((ext_vector_type(4))) float floatx4;

__device__ __forceinline__ int lower_bound(const int* __restrict__ a, int v) {
    int lo = 0, hi = NE;
    while (lo < hi) {
        int mid = (lo + hi) >> 1;
        if (a[mid] < v) lo = mid + 1; else hi = mid;
    }
    return lo;
}

__device__ __forceinline__ float sigmoidf_(float v) {
    return 1.f / (1.f + __expf(-v));
}
__device__ __forceinline__ float tanhf_(float v) {
    v = fminf(v, 40.f);
    float t = __expf(2.f * v);
    return (t - 1.f) / (t + 1.f);
}

// ---------------------------------------------------------------------------
// K1: ragged segment-sum, fp32 gather -> x fp32 written INTO d_out.
// Block 256 = (ch:8) x (b:8) x (f-chunk:4); grid C/8. edge_channel sorted ->
// per-channel contiguous edge ranges via binary search.
// ---------------------------------------------------------------------------
__global__ __launch_bounds__(256) void seg_kernel(
    const float* __restrict__ path,         // [B,P,F] fp32
    const int*   __restrict__ edge_path,    // [E]
    const int*   __restrict__ edge_channel, // [E] sorted
    float*       __restrict__ xout)         // [B,C,F] fp32 (= d_out)
{
    const int t  = threadIdx.x;
    const int cl = t >> 5;
    const int b  = (t >> 2) & 7;
    const int g  = t & 3;
    const int c  = blockIdx.x * 8 + cl;

    __shared__ int bounds[9];
    if (t < 9) bounds[t] = lower_bound(edge_channel, blockIdx.x * 8 + t);
    __syncthreads();
    const int s = bounds[cl];
    const int e = bounds[cl + 1];

    float acc[8];
    #pragma unroll
    for (int j = 0; j < 8; ++j) acc[j] = 0.f;

    const float* prow = path + (size_t)b * NP * NF + g * 8;
    for (int i = s; i < e; ++i) {
        size_t off = (size_t)edge_path[i] * NF;
        floatx4 v0 = *(const floatx4*)(prow + off);
        floatx4 v1 = *(const floatx4*)(prow + off + 4);
        #pragma unroll
        for (int j = 0; j < 4; ++j) { acc[j] += v0[j]; acc[4 + j] += v1[j]; }
    }

    const size_t idx = ((size_t)b * NC + c) * NF + g * 8;
    floatx4 o0, o1;
    #pragma unroll
    for (int j = 0; j < 4; ++j) { o0[j] = acc[j]; o1[j] = acc[4 + j]; }
    *(floatx4*)(xout + idx)     = o0;
    *(floatx4*)(xout + idx + 4) = o1;
}

// ---------------------------------------------------------------------------
// K2: pure-VALU GRU, fp32 in / fp32 out.
// Wave64 per row: lanes 0-31 (f=lane) compute the three x@W_ih^T dots for
// feature f; lanes 32-63 the three h@W_hh^T dots. W held in registers
// (one-time load, amortized over 32 rows/wave). One __shfl merges the halves.
// x is read from d_out and the result overwrites the same row (same wave,
// read-before-write in program order -> safe). Grid 2048 x 256.
// ---------------------------------------------------------------------------
__global__ __launch_bounds__(256) void gru_valu_kernel(
    const float* xbuf,                // [B*C, F] fp32 (aliases out)
    const float* __restrict__ hbuf,   // [B*C, F] fp32
    const float* __restrict__ W_ih,   // [96, 32] fp32
    const float* __restrict__ W_hh,   // [96, 32] fp32
    const float* __restrict__ b_ih,   // [96] fp32
    const float* __restrict__ b_hh,   // [96] fp32
    float* out)                       // [B*C, F] fp32 (= xbuf)
{
    const int lane = threadIdx.x & 63;
    const int wv   = threadIdx.x >> 6;
    const int f    = lane & 31;
    const bool ihh = (lane < 32);

    const float* Wb = ihh ? W_ih : W_hh;
    const float* bb = ihh ? b_ih : b_hh;

    float Wr[32], Wz[32], Wn[32];
    #pragma unroll
    for (int k4 = 0; k4 < 8; ++k4) {
        floatx4 a = *(const floatx4*)(Wb + (f) * NF + k4 * 4);
        floatx4 b = *(const floatx4*)(Wb + (32 + f) * NF + k4 * 4);
        floatx4 c = *(const floatx4*)(Wb + (64 + f) * NF + k4 * 4);
        #pragma unroll
        for (int q = 0; q < 4; ++q) {
            Wr[k4 * 4 + q] = a[q];
            Wz[k4 * 4 + q] = b[q];
            Wn[k4 * 4 + q] = c[q];
        }
    }
    const float br = bb[f], bz = bb[32 + f], bn = bb[64 + f];

    const size_t wave_id = (size_t)blockIdx.x * 4 + wv;
    for (int it = 0; it < 32; ++it) {
        const size_t row = wave_id * 32 + it;
        const float* src = ihh ? (xbuf + row * NF) : (hbuf + row * NF);
        float av[32];
        #pragma unroll
        for (int k4 = 0; k4 < 8; ++k4) {
            floatx4 v = *(const floatx4*)(src + k4 * 4);
            #pragma unroll
            for (int q = 0; q < 4; ++q) av[k4 * 4 + q] = v[q];
        }
        const float hsel = hbuf[row * NF + f];

        float ar = br, az = bz, an = bn;
        #pragma unroll
        for (int k = 0; k < 32; ++k) {
            ar = fmaf(av[k], Wr[k], ar);
            az = fmaf(av[k], Wz[k], az);
            an = fmaf(av[k], Wn[k], an);
        }

        // pull hh-half sums into ih-half lanes
        float hr = __shfl(ar, f + 32, 64);
        float hz = __shfl(az, f + 32, 64);
        float hn = __shfl(an, f + 32, 64);

        if (ihh) {
            float r = sigmoidf_(ar + hr);
            float z = sigmoidf_(az + hz);
            float n = tanhf_(an + r * hn);
            out[row * NF + f] = (1.f - z) * n + z * hsel;
        }
    }
}

extern "C" void kernel_launch(void* const* d_in, const int* in_sizes, int n_in,
                              void* d_out, int out_size, void* d_ws, size_t ws_size,
                              hipStream_t stream) {
    const float* path = (const float*)d_in[0];  // [8,65536,32] fp32
    const float* chan = (const float*)d_in[1];  // [8,32768,32] fp32
    const float* W_ih = (const float*)d_in[2];  // [96,32]
    const float* W_hh = (const float*)d_in[3];  // [96,32]
    const float* b_ih = (const float*)d_in[4];  // [96]
    const float* b_hh = (const float*)d_in[5];  // [96]
    const int* edge_path    = (const int*)d_in[6];
    const int* edge_channel = (const int*)d_in[7];
    float* out = (float*)d_out;                 // [8,32768,32] fp32

    // x (fp32) staged in d_out; K2 reads it and overwrites with the result.
    seg_kernel<<<dim3(NC / 8), dim3(256), 0, stream>>>(
        path, edge_path, edge_channel, out);
    gru_valu_kernel<<<dim3(2048), dim3(256), 0, stream>>>(
        out, chan, W_ih, W_hh, b_ih, b_hh, out);
}

// Round 8
// 259.615 us; speedup vs baseline: 1.2675x; 1.2675x over previous
//
// GRUCell2 MI355X — r8 (same as r6/r7 source; cosmetic rev to bust any
// source-hash-keyed caching after repeated container-level infra failures)
#include <hip/hip_runtime.h>

#define NB 8
#define NP 65536
#define NC 32768
#define NF 32
#define NE 524288

typedef __attribute__((ext_vector_type(4))) float floatx4;
typedef __attribute__((ext_vector_type(8))) short short8;

__device__ __forceinline__ short f2b(float f) {
    union { float f; unsigned int u; } v;
    v.f = f;
    unsigned int lsb = (v.u >> 16) & 1u;
    v.u += 0x7fffu + lsb;   // round-to-nearest-even
    return (short)(v.u >> 16);
}

__device__ __forceinline__ int lower_bound(const int* __restrict__ a, int v) {
    int lo = 0, hi = NE;
    while (lo < hi) {
        int mid = (lo + hi) >> 1;
        if (a[mid] < v) lo = mid + 1; else hi = mid;
    }
    return lo;
}

__device__ __forceinline__ float sigmoidf_(float v) {
    return 1.f / (1.f + __expf(-v));
}
__device__ __forceinline__ float tanhf_(float v) {
    v = fminf(v, 40.f);
    float t = __expf(2.f * v);
    return (t - 1.f) / (t + 1.f);
}

// ---------------------------------------------------------------------------
// K1: ragged segment-sum, fp32 gather -> x fp32 written INTO d_out.
// Block 256 = (ch:8) x (b:8) x (f-chunk:4); grid C/8. edge_channel sorted ->
// per-channel contiguous ranges via binary search. Unroll-by-4 keeps 4
// independent index+gather chains in flight (latency hiding; K1 was
// dependent-load-latency bound at 185 us).
// ---------------------------------------------------------------------------
__global__ __launch_bounds__(256) void seg_kernel(
    const float* __restrict__ path,         // [B,P,F] fp32
    const int*   __restrict__ edge_path,    // [E]
    const int*   __restrict__ edge_channel, // [E] sorted
    float*       __restrict__ xout)         // [B,C,F] fp32 (= d_out)
{
    const int t  = threadIdx.x;
    const int cl = t >> 5;
    const int b  = (t >> 2) & 7;
    const int g  = t & 3;
    const int c  = blockIdx.x * 8 + cl;

    __shared__ int bounds[9];
    if (t < 9) bounds[t] = lower_bound(edge_channel, blockIdx.x * 8 + t);
    __syncthreads();
    const int s = bounds[cl];
    const int e = bounds[cl + 1];

    float acc[8];
    #pragma unroll
    for (int j = 0; j < 8; ++j) acc[j] = 0.f;

    const float* prow = path + (size_t)b * NP * NF + g * 8;

    int i = s;
    for (; i + 4 <= e; i += 4) {
        size_t o0 = (size_t)edge_path[i]     * NF;
        size_t o1 = (size_t)edge_path[i + 1] * NF;
        size_t o2 = (size_t)edge_path[i + 2] * NF;
        size_t o3 = (size_t)edge_path[i + 3] * NF;
        floatx4 a0 = *(const floatx4*)(prow + o0), b0 = *(const floatx4*)(prow + o0 + 4);
        floatx4 a1 = *(const floatx4*)(prow + o1), b1 = *(const floatx4*)(prow + o1 + 4);
        floatx4 a2 = *(const floatx4*)(prow + o2), b2 = *(const floatx4*)(prow + o2 + 4);
        floatx4 a3 = *(const floatx4*)(prow + o3), b3 = *(const floatx4*)(prow + o3 + 4);
        #pragma unroll
        for (int j = 0; j < 4; ++j) {
            acc[j]     += a0[j] + a1[j] + a2[j] + a3[j];
            acc[4 + j] += b0[j] + b1[j] + b2[j] + b3[j];
        }
    }
    for (; i < e; ++i) {
        size_t off = (size_t)edge_path[i] * NF;
        floatx4 v0 = *(const floatx4*)(prow + off);
        floatx4 v1 = *(const floatx4*)(prow + off + 4);
        #pragma unroll
        for (int j = 0; j < 4; ++j) { acc[j] += v0[j]; acc[4 + j] += v1[j]; }
    }

    const size_t idx = ((size_t)b * NC + c) * NF + g * 8;
    floatx4 o0, o1;
    #pragma unroll
    for (int j = 0; j < 4; ++j) { o0[j] = acc[j]; o1[j] = acc[4 + j]; }
    *(floatx4*)(xout + idx)     = o0;
    *(floatx4*)(xout + idx + 4) = o1;
}

// ---------------------------------------------------------------------------
// K2: fused GRU via mfma_f32_16x16x32_bf16 (values verified: rounds 2 & 3
// computed identical results with MFMA vs pure-VALU engines).
// [262144 x 32] @ [32 x 96] twice, K=32 in one MFMA. Wave owns 16 consecutive
// rows. A-frag A[m=lane&15][k=quad*8+j] loaded from global fp32, converted to
// bf16 in-register; W B-frags likewise. Epilogue in C-layout (col=lane&15,
// row=quad*4+reg), fp32 h for the z*h blend, fp32 out. xbuf aliases out
// (wave-private rows, read-before-write -> safe).
// ---------------------------------------------------------------------------
__global__ __launch_bounds__(256) void gru_kernel(
    const float* xbuf,                     // [B*C, F] fp32 (aliases out!)
    const float* __restrict__ hbuf,        // [B*C, F] fp32
    const float* __restrict__ W_ih,        // [96, 32] fp32
    const float* __restrict__ W_hh,        // [96, 32] fp32
    const float* __restrict__ b_ih,        // [96] fp32
    const float* __restrict__ b_hh,        // [96] fp32
    float* out)                            // [B*C, F] fp32
{
    const int wave = threadIdx.x >> 6;
    const int lane = threadIdx.x & 63;
    const int quad = lane >> 4;
    const int n16  = lane & 15;
    const int k0   = quad * 8;
    const size_t mbase = (size_t)blockIdx.x * 64 + (size_t)wave * 16;

    // B-frags: B[k=quad*8+j][n=lane&15] = W[16t+n16][k0+j] (row-contig fp32)
    short8 bwx[6], bwh[6];
    float  bx[6], bh[6];
    #pragma unroll
    for (int tt = 0; tt < 6; ++tt) {
        int j = 16 * tt + n16;
        floatx4 wx0 = *(const floatx4*)(W_ih + j * NF + k0);
        floatx4 wx1 = *(const floatx4*)(W_ih + j * NF + k0 + 4);
        floatx4 wh0 = *(const floatx4*)(W_hh + j * NF + k0);
        floatx4 wh1 = *(const floatx4*)(W_hh + j * NF + k0 + 4);
        #pragma unroll
        for (int q = 0; q < 4; ++q) {
            bwx[tt][q]     = f2b(wx0[q]);
            bwx[tt][4 + q] = f2b(wx1[q]);
            bwh[tt][q]     = f2b(wh0[q]);
            bwh[tt][4 + q] = f2b(wh1[q]);
        }
        bx[tt] = b_ih[j];
        bh[tt] = b_hh[j];
    }

    floatx4 x0 = *(const floatx4*)(xbuf + (mbase + n16) * NF + k0);
    floatx4 x1 = *(const floatx4*)(xbuf + (mbase + n16) * NF + k0 + 4);
    floatx4 h0 = *(const floatx4*)(hbuf + (mbase + n16) * NF + k0);
    floatx4 h1 = *(const floatx4*)(hbuf + (mbase + n16) * NF + k0 + 4);
    short8 ax, ah;
    #pragma unroll
    for (int q = 0; q < 4; ++q) {
        ax[q] = f2b(x0[q]); ax[4 + q] = f2b(x1[q]);
        ah[q] = f2b(h0[q]); ah[4 + q] = f2b(h1[q]);
    }

    floatx4 accx[6], acch[6];
    #pragma unroll
    for (int tt = 0; tt < 6; ++tt) {
        floatx4 z4 = {0.f, 0.f, 0.f, 0.f};
        accx[tt] = __builtin_amdgcn_mfma_f32_16x16x32_bf16(ax, bwx[tt], z4, 0, 0, 0);
        acch[tt] = __builtin_amdgcn_mfma_f32_16x16x32_bf16(ah, bwh[tt], z4, 0, 0, 0);
    }

    // Gate order (PyTorch): r = tiles 0-1, z = tiles 2-3, n = tiles 4-5.
    #pragma unroll
    for (int i = 0; i < 4; ++i) {
        size_t m = mbase + quad * 4 + i;
        float r0 = sigmoidf_(accx[0][i] + bx[0] + acch[0][i] + bh[0]);
        float r1 = sigmoidf_(accx[1][i] + bx[1] + acch[1][i] + bh[1]);
        float z0 = sigmoidf_(accx[2][i] + bx[2] + acch[2][i] + bh[2]);
        float z1 = sigmoidf_(accx[3][i] + bx[3] + acch[3][i] + bh[3]);
        float n0 = tanhf_(accx[4][i] + bx[4] + r0 * (acch[4][i] + bh[4]));
        float n1 = tanhf_(accx[5][i] + bx[5] + r1 * (acch[5][i] + bh[5]));
        float hv0 = hbuf[m * NF + n16];
        float hv1 = hbuf[m * NF + 16 + n16];
        out[m * NF + n16]      = (1.f - z0) * n0 + z0 * hv0;
        out[m * NF + 16 + n16] = (1.f - z1) * n1 + z1 * hv1;
    }
}

extern "C" void kernel_launch(void* const* d_in, const int* in_sizes, int n_in,
                              void* d_out, int out_size, void* d_ws, size_t ws_size,
                              hipStream_t stream) {
    const float* path = (const float*)d_in[0];  // [8,65536,32] fp32
    const float* chan = (const float*)d_in[1];  // [8,32768,32] fp32
    const float* W_ih = (const float*)d_in[2];  // [96,32]
    const float* W_hh = (const float*)d_in[3];  // [96,32]
    const float* b_ih = (const float*)d_in[4];  // [96]
    const float* b_hh = (const float*)d_in[5];  // [96]
    const int* edge_path    = (const int*)d_in[6];
    const int* edge_channel = (const int*)d_in[7];
    float* out = (float*)d_out;                 // [8,32768,32] fp32

    // x (fp32) staged in d_out; K2 reads it and overwrites with the result.
    seg_kernel<<<dim3(NC / 8), dim3(256), 0, stream>>>(
        path, edge_path, edge_channel, out);
    gru_kernel<<<dim3((NB * NC) / 64), dim3(256), 0, stream>>>(
        out, chan, W_ih, W_hh, b_ih, b_hh, out);
}